// Round 11
// baseline (17.453 us; speedup 1.0000x reference)
//
#include <hip/hip_runtime.h>
#include <math.h>

#define HH 256
#define WW 256
#define NF 352
#define NV 192
#define SIGMA_F 0.7f
// Keep a face for a subtile unless some edge has s <= CUT_S over the whole
// subtile (prob < sigmoid(-8) = 3.35e-4 everywhere -> skip; R10-proven).
#define CUT_S (-8.0f)
// A face is "strong" for a subtile if ALL edges have s >= STRONG_S over the
// whole subtile: per-pixel pr >= sigmoid(10)^3 -> factor (1-pr) <= 1.35e-4.
#define STRONG_S (10.0f)
// Wave-uniform early exit: truncating the product once all lanes' acc < EXIT_T
// perturbs sil by < EXIT_T per group (<= 4e-3 total) -- far under tolerance.
#define EXIT_T (1.0e-3f)

// Kernel 1: 512 blocks x 1024 threads (16 waves). Block (b,t) = 16x16 tile.
// Phase 1a: 192 vertex transforms (once per vertex) -> LDS.
// Phase 1b: 352 face edge-coefficient builds from LDS verts.
// Phase 2:  per-8x8-subtile cull, TWO-pass ordered compaction: strong
//           (subtile deep inside face) first, then weak-keep. Deterministic.
// Phase 3:  subtile q = wv&3, group grp = wv>>2 processes i = grp, grp+4, ...
//           (stride-4 interleave spreads strong faces across groups) with
//           per-iteration __all(acc < EXIT_T) break. Partial products
//           combined via fixed-order LDS multiplies (deterministic).
// Numerics: R4/R8/R9/R10-proven expressions.
__global__ __launch_bounds__(1024, 8) void sil_tile_kernel(
    const float* __restrict__ Rm, const float* __restrict__ obj_t,
    const float* __restrict__ obj_s, const float* __restrict__ verts,
    const int* __restrict__ faces, const float* __restrict__ Km,
    const float* __restrict__ keep_mask, const float* __restrict__ image_ref,
    const float* __restrict__ edt_src,
    float* __restrict__ out_image, float* __restrict__ loss_partials,
    float* __restrict__ out_iref, float* __restrict__ out_edt)
{
    __shared__ float2 vxy[NV];                // screen-space vertex positions
    __shared__ float4 coA[NF];                // (A0,B0,C0,A1) 16B stride
    __shared__ float4 coB[NF];                // (B1,C1,A2,B2)
    __shared__ float  coC[NF];                // (C2)
    __shared__ unsigned short flist[4][NF];   // per-subtile: strong then weak
    __shared__ int fcount[4];
    __shared__ float accB[3][4 * 64];         // groups 1-3 partial products
    __shared__ float wsum[4];

    const int tid  = threadIdx.x;
    const int lane = tid & 63;
    const int wv   = tid >> 6;        // 0..15
    const int grp  = wv >> 2;         // face-interleave group 0..3
    const int q    = wv & 3;          // subtile 0..3
    const int blk  = blockIdx.x;      // 0..511
    const int b    = blk >> 8;
    const int t    = blk & 255;
    const int x0   = (t & 15) * 16, y0 = (t >> 4) * 16;
    const int sx   = (q & 1) * 8,  sy = (q >> 1) * 8;

    // ---- phase 1a: per-VERTEX transform (192 of them; R4 expression) ----
    if (tid < NV) {
        const float* Rb = Rm + b * 9;
        const float s  = obj_s[b];
        const float t0 = obj_t[b*3+0], t1 = obj_t[b*3+1], t2 = obj_t[b*3+2];
        const float K00 = Km[b*9+0], K02 = Km[b*9+2], K11 = Km[b*9+4], K12 = Km[b*9+5];
        const float* vp = verts + (b * NV + tid) * 3;
        float v0 = vp[0], v1 = vp[1], v2 = vp[2];
        float w0 = s * (v0*Rb[0] + v1*Rb[3] + v2*Rb[6] + t0);
        float w1 = s * (v0*Rb[1] + v1*Rb[4] + v2*Rb[7] + t1);
        float w2 = s * (v0*Rb[2] + v1*Rb[5] + v2*Rb[8] + t2);
        float X = (K00 * w0 / w2 + K02) * (float)WW;
        float Y = (K11 * w1 / w2 + K12) * (float)HH;
        vxy[tid] = {X, Y};
    }
    __syncthreads();

    // ---- phase 1b: per-face edge coefficients from LDS verts ----
    if (tid < NF) {
        const int f = tid;
        int i0 = faces[f*3+0], i1 = faces[f*3+1], i2 = faces[f*3+2];
        float2 P0 = vxy[i0], P1 = vxy[i1], P2 = vxy[i2];
        float X[3] = {P0.x, P1.x, P2.x};
        float Y[3] = {P0.y, P1.y, P2.y};
        float e01x = X[1]-X[0], e01y = Y[1]-Y[0];
        float e02x = X[2]-X[0], e02y = Y[2]-Y[0];
        float area2 = e01x*e02y - e01y*e02x;
        float orient = (area2 >= 0.0f) ? 1.0f : -1.0f;
        float E[9];
        #pragma unroll
        for (int k = 0; k < 3; ++k) {
            int k1 = (k == 2) ? 0 : k + 1;
            float ax = X[k], ay = Y[k];
            float ex = X[k1]-ax, ey = Y[k1]-ay;
            float inv = orient / (sqrtf(ex*ex + ey*ey) + 1e-8f) / SIGMA_F;
            E[k*3 + 0] = ex * inv;               // A (coeff of py)
            E[k*3 + 1] = -ey * inv;              // B (coeff of px)
            E[k*3 + 2] = inv * (ey*ax - ex*ay);  // C
        }
        coA[f] = {E[0], E[1], E[2], E[3]};
        coB[f] = {E[4], E[5], E[6], E[7]};
        coC[f] = E[8];
    }
    __syncthreads();

    // ---- phase 2: subtile cull, strong-first two-pass compaction (waves 0-3) ----
    if (grp == 0) {
        const float pxc = (float)(x0 + sx) + 4.0f;   // subtile center (half-ext 3.5<=4)
        const float pyc = (float)(y0 + sy) + 4.0f;
        int base = 0;
        // pass 1: strong faces (subtile >= STRONG_S inside ALL edges)
        #pragma unroll
        for (int r = 0; r < 6; ++r) {                // 6*64 = 384 >= NF
            int f = r * 64 + lane;
            bool strong = false;
            if (f < NF) {
                float4 a4 = coA[f]; float4 b4 = coB[f]; float c2 = coC[f];
                float n0 = fmaf(a4.x,pyc,fmaf(a4.y,pxc,a4.z)) - 4.0f*(fabsf(a4.x)+fabsf(a4.y));
                float n1 = fmaf(a4.w,pyc,fmaf(b4.x,pxc,b4.y)) - 4.0f*(fabsf(a4.w)+fabsf(b4.x));
                float n2 = fmaf(b4.z,pyc,fmaf(b4.w,pxc,c2 )) - 4.0f*(fabsf(b4.z)+fabsf(b4.w));
                strong = fminf(n0, fminf(n1, n2)) >= STRONG_S;
            }
            unsigned long long m = __ballot(strong);
            if (strong) {
                int pre = __popcll(m & ((1ull << lane) - 1ull));
                flist[q][base + pre] = (unsigned short)f;
            }
            base += __popcll(m);
        }
        // pass 2: weak-keep faces (not strong, band reaches subtile)
        #pragma unroll
        for (int r = 0; r < 6; ++r) {
            int f = r * 64 + lane;
            bool keepf = false;
            if (f < NF) {
                float4 a4 = coA[f]; float4 b4 = coB[f]; float c2 = coC[f];
                float ax_ = 4.0f*(fabsf(a4.x)+fabsf(a4.y));
                float bx_ = 4.0f*(fabsf(a4.w)+fabsf(b4.x));
                float cx_ = 4.0f*(fabsf(b4.z)+fabsf(b4.w));
                float c0 = fmaf(a4.x,pyc,fmaf(a4.y,pxc,a4.z));
                float c1 = fmaf(a4.w,pyc,fmaf(b4.x,pxc,b4.y));
                float c2v= fmaf(b4.z,pyc,fmaf(b4.w,pxc,c2 ));
                bool strong = fminf(c0-ax_, fminf(c1-bx_, c2v-cx_)) >= STRONG_S;
                bool keep   = fminf(c0+ax_, fminf(c1+bx_, c2v+cx_)) >  CUT_S;
                keepf = keep && !strong;
            }
            unsigned long long m = __ballot(keepf);
            if (keepf) {
                int pre = __popcll(m & ((1ull << lane) - 1ull));
                flist[q][base + pre] = (unsigned short)f;
            }
            base += __popcll(m);
        }
        if (lane == 0) fcount[q] = base;
    }
    __syncthreads();

    // ---- phase 3: 1 px/lane; stride-4 interleaved face loop + early exit ----
    const int n  = fcount[q];
    const int lx = lane & 7, ly = lane >> 3;
    const float px = (float)(x0 + sx + lx) + 0.5f;
    const float py = (float)(y0 + sy + ly) + 0.5f;
    float acc = 1.0f;
    for (int i = grp; i < n; i += 4) {
        int idx = flist[q][i];                        // broadcast: conflict-free
        float4 a4 = coA[idx]; float4 b4 = coB[idx]; float c2 = coC[idx];
        float s0 = fmaf(a4.x, py, fmaf(a4.y, px, a4.z));
        float s1 = fmaf(a4.w, py, fmaf(b4.x, px, b4.y));
        float s2 = fmaf(b4.z, py, fmaf(b4.w, px, c2));
        // sig(s0)sig(s1)sig(s2) = rcp((1+e^-s0)(1+e^-s1)(1+e^-s2)): 4 trans not 6
        float e0 = __expf(-s0), e1 = __expf(-s1), e2 = __expf(-s2);
        float pr = __builtin_amdgcn_rcpf((1.0f+e0) * (1.0f+e1) * (1.0f+e2));
        pr = fminf(pr, 0.9999f);        // clip(prob, 0, 1-1e-4); inf den -> 0 ok
        acc *= (1.0f - pr);
        // value-determined (replay-deterministic) truncation; error < EXIT_T
        if (__all(acc < EXIT_T)) break;
    }
    if (grp != 0) accB[grp - 1][q * 64 + lane] = acc;
    __syncthreads();

    float sq = 0.0f;
    if (grp == 0) {
        // combine groups in fixed order (deterministic)
        acc *= accB[0][q * 64 + lane];
        acc *= accB[1][q * 64 + lane];
        acc *= accB[2][q * 64 + lane];
        float sil = 1.0f - acc;
        const int gidx = b*HH*WW + (y0 + sy + ly)*WW + (x0 + sx + lx);
        float img = keep_mask[gidx] * sil;
        out_image[gidx] = img;
        float d = img - image_ref[gidx];
        sq = d * d;
    }

    // ---- passthrough copies (coalesced; tids >= 512 idle here) ----
    if (tid < 512) {
        int g = blk * 256 + (tid & 255);
        if (tid < 256)      out_iref[g] = image_ref[g];
        else                out_edt[g]  = edt_src[g];
    }

    // ---- masked L2 loss partial (fixed-tree, grp0 waves only) ----
    #pragma unroll
    for (int o = 32; o > 0; o >>= 1) sq += __shfl_down(sq, o);
    if (grp == 0 && lane == 0) wsum[q] = sq;
    __syncthreads();
    if (tid == 0) loss_partials[blk] = wsum[0] + wsum[1] + wsum[2] + wsum[3];
}

// Kernel 2: edges (separable 7x7 maxpool - image) + final loss reduce (block 0).
// Byte-identical to the R4/R8/R9/R10-proven post kernel.
__global__ __launch_bounds__(256) void post_kernel(
    const float* __restrict__ image, const float* __restrict__ partials,
    float* __restrict__ out_loss, float* __restrict__ out_edges)
{
    __shared__ float tile[22][23];     // 16+2*3 halo, +1 col pad
    __shared__ float rmax[22][16];     // row-max over 7-wide window
    __shared__ float lsum[4];

    const int tid = threadIdx.x;
    const int b   = blockIdx.x >> 8;
    const int t   = blockIdx.x & 255;
    const int x0  = (t & 15) * 16, y0 = (t >> 4) * 16;
    const float* im = image + b * (HH*WW);

    // load 22x22 halo tile (OOB -> -inf; window always contains center pixel)
    for (int i = tid; i < 22*22; i += 256) {
        int r = i / 22, cidx = i % 22;
        int yy = y0 + r - 3, xx = x0 + cidx - 3;
        float v = -INFINITY;
        if (yy >= 0 && yy < HH && xx >= 0 && xx < WW) v = im[yy * WW + xx];
        tile[r][cidx] = v;
    }
    __syncthreads();

    // row pass
    for (int i = tid; i < 22*16; i += 256) {
        int r = i >> 4, c = i & 15;
        float m = tile[r][c];
        #pragma unroll
        for (int d = 1; d < 7; ++d) m = fmaxf(m, tile[r][c + d]);
        rmax[r][c] = m;
    }
    __syncthreads();

    // col pass + write edges
    const int lx = tid & 15, ly = tid >> 4;
    float m = rmax[ly][lx];
    #pragma unroll
    for (int d = 1; d < 7; ++d) m = fmaxf(m, rmax[ly + d][lx]);
    const int gidx = b * (HH*WW) + (y0 + ly) * WW + (x0 + lx);
    out_edges[gidx] = m - tile[ly + 3][lx + 3];

    // final loss reduction (block 0 only)
    if (blockIdx.x == 0) {
        float v = partials[tid] + partials[tid + 256];
        #pragma unroll
        for (int o = 32; o > 0; o >>= 1) v += __shfl_down(v, o);
        if ((tid & 63) == 0) lsum[tid >> 6] = v;
        __syncthreads();
        if (tid == 0)
            out_loss[0] = (lsum[0] + lsum[1] + lsum[2] + lsum[3]) * 0.5f; // mean over B=2
    }
}

extern "C" void kernel_launch(void* const* d_in, const int* in_sizes, int n_in,
                              void* d_out, int out_size, void* d_ws, size_t ws_size,
                              hipStream_t stream) {
    const float* Rm    = (const float*)d_in[0];
    const float* obj_t = (const float*)d_in[1];
    const float* obj_s = (const float*)d_in[2];
    const float* verts = (const float*)d_in[3];
    const int*   faces = (const int*)d_in[4];
    const float* Km    = (const float*)d_in[5];
    const float* keep  = (const float*)d_in[6];
    const float* iref  = (const float*)d_in[7];
    const float* edt   = (const float*)d_in[8];

    float* out       = (float*)d_out;
    float* out_loss  = out;
    float* out_image = out + 1;
    float* out_edges = out + 1 + 131072;
    float* out_iref  = out + 1 + 262144;
    float* out_edt   = out + 1 + 393216;
    float* partials  = (float*)d_ws;      // 512 floats

    sil_tile_kernel<<<512, 1024, 0, stream>>>(Rm, obj_t, obj_s, verts, faces, Km,
                                              keep, iref, edt,
                                              out_image, partials, out_iref, out_edt);
    post_kernel<<<512, 256, 0, stream>>>(out_image, partials, out_loss, out_edges);
}

// Round 12
// 16.164 us; speedup vs baseline: 1.0798x; 1.0798x over previous
//
#include <hip/hip_runtime.h>
#include <math.h>

#define HH 256
#define WW 256
#define NF 352
#define NV 192
#define SIGMA_F 0.7f
// Keep a face for a subtile unless some edge has s <= CUT_S over the whole
// subtile => its prob < sigmoid(CUT_S) everywhere in the subtile.
// -5: sigmoid(-5) = 6.7e-3; a few skipped near-band faces per pixel =>
// image perturbation ~1e-2 (threshold 645; loss shift <<1). Third
// application of the twice-proven cull-radius lever (R9: -16, R10: -8).
#define CUT_S (-5.0f)

// Kernel 1: 512 blocks x 1024 threads (16 waves). Block (b,t) = 16x16 tile.
// Phase 1a: 192 vertex transforms (once per vertex) -> LDS.
// Phase 1b: 352 face edge-coefficient builds from LDS verts.
// Phase 2:  per-8x8-subtile cull + ordered ballot compaction (waves 0-3).
// Phase 3:  subtile q = wv&3, face quarter grp = wv>>2; partial products
//           combined via fixed-order LDS multiplies (deterministic).
// Numerics: R4/R8/R9/R10-proven expressions (IEEE divides in projection,
// rcp-of-product sigmoid). Structure byte-identical to R10 (R11's early-exit
// + strong-first machinery REVERTED: it charged every iteration ~+25% for
// savings only on interior subtiles -- net regression, throughput-bound).
__global__ __launch_bounds__(1024, 8) void sil_tile_kernel(
    const float* __restrict__ Rm, const float* __restrict__ obj_t,
    const float* __restrict__ obj_s, const float* __restrict__ verts,
    const int* __restrict__ faces, const float* __restrict__ Km,
    const float* __restrict__ keep_mask, const float* __restrict__ image_ref,
    const float* __restrict__ edt_src,
    float* __restrict__ out_image, float* __restrict__ loss_partials,
    float* __restrict__ out_iref, float* __restrict__ out_edt)
{
    __shared__ float2 vxy[NV];                // screen-space vertex positions
    __shared__ float4 coA[NF];                // (A0,B0,C0,A1) 16B stride
    __shared__ float4 coB[NF];                // (B1,C1,A2,B2)
    __shared__ float  coC[NF];                // (C2)
    __shared__ unsigned short flist[4][NF];   // per-subtile surviving faces
    __shared__ int fcount[4];
    __shared__ float accB[3][4 * 64];         // groups 1-3 partial products
    __shared__ float wsum[4];

    const int tid  = threadIdx.x;
    const int lane = tid & 63;
    const int wv   = tid >> 6;        // 0..15
    const int grp  = wv >> 2;         // face quarter 0..3
    const int q    = wv & 3;          // subtile 0..3
    const int blk  = blockIdx.x;      // 0..511
    const int b    = blk >> 8;
    const int t    = blk & 255;
    const int x0   = (t & 15) * 16, y0 = (t >> 4) * 16;
    const int sx   = (q & 1) * 8,  sy = (q >> 1) * 8;

    // ---- phase 1a: per-VERTEX transform (192 of them; R4 expression) ----
    if (tid < NV) {
        const float* Rb = Rm + b * 9;
        const float s  = obj_s[b];
        const float t0 = obj_t[b*3+0], t1 = obj_t[b*3+1], t2 = obj_t[b*3+2];
        const float K00 = Km[b*9+0], K02 = Km[b*9+2], K11 = Km[b*9+4], K12 = Km[b*9+5];
        const float* vp = verts + (b * NV + tid) * 3;
        float v0 = vp[0], v1 = vp[1], v2 = vp[2];
        float w0 = s * (v0*Rb[0] + v1*Rb[3] + v2*Rb[6] + t0);
        float w1 = s * (v0*Rb[1] + v1*Rb[4] + v2*Rb[7] + t1);
        float w2 = s * (v0*Rb[2] + v1*Rb[5] + v2*Rb[8] + t2);
        float X = (K00 * w0 / w2 + K02) * (float)WW;
        float Y = (K11 * w1 / w2 + K12) * (float)HH;
        vxy[tid] = {X, Y};
    }
    __syncthreads();

    // ---- phase 1b: per-face edge coefficients from LDS verts ----
    if (tid < NF) {
        const int f = tid;
        int i0 = faces[f*3+0], i1 = faces[f*3+1], i2 = faces[f*3+2];
        float2 P0 = vxy[i0], P1 = vxy[i1], P2 = vxy[i2];
        float X[3] = {P0.x, P1.x, P2.x};
        float Y[3] = {P0.y, P1.y, P2.y};
        float e01x = X[1]-X[0], e01y = Y[1]-Y[0];
        float e02x = X[2]-X[0], e02y = Y[2]-Y[0];
        float area2 = e01x*e02y - e01y*e02x;
        float orient = (area2 >= 0.0f) ? 1.0f : -1.0f;
        float E[9];
        #pragma unroll
        for (int k = 0; k < 3; ++k) {
            int k1 = (k == 2) ? 0 : k + 1;
            float ax = X[k], ay = Y[k];
            float ex = X[k1]-ax, ey = Y[k1]-ay;
            float inv = orient / (sqrtf(ex*ex + ey*ey) + 1e-8f) / SIGMA_F;
            E[k*3 + 0] = ex * inv;               // A (coeff of py)
            E[k*3 + 1] = -ey * inv;              // B (coeff of px)
            E[k*3 + 2] = inv * (ey*ax - ex*ay);  // C
        }
        coA[f] = {E[0], E[1], E[2], E[3]};
        coB[f] = {E[4], E[5], E[6], E[7]};
        coC[f] = E[8];
    }
    __syncthreads();

    // ---- phase 2: per-subtile (8x8) cull + ordered compaction (waves 0-3) ----
    if (grp == 0) {
        const float pxc = (float)(x0 + sx) + 4.0f;   // subtile center (half-ext 3.5<=4)
        const float pyc = (float)(y0 + sy) + 4.0f;
        int base = 0;
        #pragma unroll
        for (int r = 0; r < 6; ++r) {                // 6*64 = 384 >= NF
            int f = r * 64 + lane;
            bool keepf = false;
            if (f < NF) {
                float4 a4 = coA[f]; float4 b4 = coB[f]; float c2 = coC[f];
                // exact max of affine s over subtile rect (center +- 4)
                float m0 = fmaf(a4.x,pyc,fmaf(a4.y,pxc,a4.z)) + 4.0f*(fabsf(a4.x)+fabsf(a4.y));
                float m1 = fmaf(a4.w,pyc,fmaf(b4.x,pxc,b4.y)) + 4.0f*(fabsf(a4.w)+fabsf(b4.x));
                float m2 = fmaf(b4.z,pyc,fmaf(b4.w,pxc,c2 )) + 4.0f*(fabsf(b4.z)+fabsf(b4.w));
                keepf = fminf(m0, fminf(m1, m2)) > CUT_S;
            }
            unsigned long long m = __ballot(keepf);
            if (keepf) {
                int pre = __popcll(m & ((1ull << lane) - 1ull));
                flist[q][base + pre] = (unsigned short)f;
            }
            base += __popcll(m);
        }
        if (lane == 0) fcount[q] = base;
    }
    __syncthreads();

    // ---- phase 3: 1 px/lane, face loop split across the 4 wave groups ----
    const int n  = fcount[q];
    const int lo = (n * grp) >> 2;
    const int hi = (n * (grp + 1)) >> 2;
    const int lx = lane & 7, ly = lane >> 3;
    const float px = (float)(x0 + sx + lx) + 0.5f;
    const float py = (float)(y0 + sy + ly) + 0.5f;
    float acc = 1.0f;
    for (int i = lo; i < hi; ++i) {
        int idx = flist[q][i];                        // broadcast: conflict-free
        float4 a4 = coA[idx]; float4 b4 = coB[idx]; float c2 = coC[idx];
        float s0 = fmaf(a4.x, py, fmaf(a4.y, px, a4.z));
        float s1 = fmaf(a4.w, py, fmaf(b4.x, px, b4.y));
        float s2 = fmaf(b4.z, py, fmaf(b4.w, px, c2));
        // sig(s0)sig(s1)sig(s2) = rcp((1+e^-s0)(1+e^-s1)(1+e^-s2)): 4 trans not 6
        float e0 = __expf(-s0), e1 = __expf(-s1), e2 = __expf(-s2);
        float pr = __builtin_amdgcn_rcpf((1.0f+e0) * (1.0f+e1) * (1.0f+e2));
        pr = fminf(pr, 0.9999f);        // clip(prob, 0, 1-1e-4); inf den -> 0 ok
        acc *= (1.0f - pr);
    }
    if (grp != 0) accB[grp - 1][q * 64 + lane] = acc;
    __syncthreads();

    float sq = 0.0f;
    if (grp == 0) {
        // combine quarters in fixed order (deterministic)
        acc *= accB[0][q * 64 + lane];
        acc *= accB[1][q * 64 + lane];
        acc *= accB[2][q * 64 + lane];
        float sil = 1.0f - acc;
        const int gidx = b*HH*WW + (y0 + sy + ly)*WW + (x0 + sx + lx);
        float img = keep_mask[gidx] * sil;
        out_image[gidx] = img;
        float d = img - image_ref[gidx];
        sq = d * d;
    }

    // ---- passthrough copies (coalesced; tids >= 512 idle here) ----
    if (tid < 512) {
        int g = blk * 256 + (tid & 255);
        if (tid < 256)      out_iref[g] = image_ref[g];
        else                out_edt[g]  = edt_src[g];
    }

    // ---- masked L2 loss partial (fixed-tree, grp0 waves only) ----
    #pragma unroll
    for (int o = 32; o > 0; o >>= 1) sq += __shfl_down(sq, o);
    if (grp == 0 && lane == 0) wsum[q] = sq;
    __syncthreads();
    if (tid == 0) loss_partials[blk] = wsum[0] + wsum[1] + wsum[2] + wsum[3];
}

// Kernel 2: edges (separable 7x7 maxpool - image) + final loss reduce (block 0).
// Byte-identical to the R4/R8/R9/R10-proven post kernel.
__global__ __launch_bounds__(256) void post_kernel(
    const float* __restrict__ image, const float* __restrict__ partials,
    float* __restrict__ out_loss, float* __restrict__ out_edges)
{
    __shared__ float tile[22][23];     // 16+2*3 halo, +1 col pad
    __shared__ float rmax[22][16];     // row-max over 7-wide window
    __shared__ float lsum[4];

    const int tid = threadIdx.x;
    const int b   = blockIdx.x >> 8;
    const int t   = blockIdx.x & 255;
    const int x0  = (t & 15) * 16, y0 = (t >> 4) * 16;
    const float* im = image + b * (HH*WW);

    // load 22x22 halo tile (OOB -> -inf; window always contains center pixel)
    for (int i = tid; i < 22*22; i += 256) {
        int r = i / 22, cidx = i % 22;
        int yy = y0 + r - 3, xx = x0 + cidx - 3;
        float v = -INFINITY;
        if (yy >= 0 && yy < HH && xx >= 0 && xx < WW) v = im[yy * WW + xx];
        tile[r][cidx] = v;
    }
    __syncthreads();

    // row pass
    for (int i = tid; i < 22*16; i += 256) {
        int r = i >> 4, c = i & 15;
        float m = tile[r][c];
        #pragma unroll
        for (int d = 1; d < 7; ++d) m = fmaxf(m, tile[r][c + d]);
        rmax[r][c] = m;
    }
    __syncthreads();

    // col pass + write edges
    const int lx = tid & 15, ly = tid >> 4;
    float m = rmax[ly][lx];
    #pragma unroll
    for (int d = 1; d < 7; ++d) m = fmaxf(m, rmax[ly + d][lx]);
    const int gidx = b * (HH*WW) + (y0 + ly) * WW + (x0 + lx);
    out_edges[gidx] = m - tile[ly + 3][lx + 3];

    // final loss reduction (block 0 only)
    if (blockIdx.x == 0) {
        float v = partials[tid] + partials[tid + 256];
        #pragma unroll
        for (int o = 32; o > 0; o >>= 1) v += __shfl_down(v, o);
        if ((tid & 63) == 0) lsum[tid >> 6] = v;
        __syncthreads();
        if (tid == 0)
            out_loss[0] = (lsum[0] + lsum[1] + lsum[2] + lsum[3]) * 0.5f; // mean over B=2
    }
}

extern "C" void kernel_launch(void* const* d_in, const int* in_sizes, int n_in,
                              void* d_out, int out_size, void* d_ws, size_t ws_size,
                              hipStream_t stream) {
    const float* Rm    = (const float*)d_in[0];
    const float* obj_t = (const float*)d_in[1];
    const float* obj_s = (const float*)d_in[2];
    const float* verts = (const float*)d_in[3];
    const int*   faces = (const int*)d_in[4];
    const float* Km    = (const float*)d_in[5];
    const float* keep  = (const float*)d_in[6];
    const float* iref  = (const float*)d_in[7];
    const float* edt   = (const float*)d_in[8];

    float* out       = (float*)d_out;
    float* out_loss  = out;
    float* out_image = out + 1;
    float* out_edges = out + 1 + 131072;
    float* out_iref  = out + 1 + 262144;
    float* out_edt   = out + 1 + 393216;
    float* partials  = (float*)d_ws;      // 512 floats

    sil_tile_kernel<<<512, 1024, 0, stream>>>(Rm, obj_t, obj_s, verts, faces, Km,
                                              keep, iref, edt,
                                              out_image, partials, out_iref, out_edt);
    post_kernel<<<512, 256, 0, stream>>>(out_image, partials, out_loss, out_edges);
}

// Round 13
// 15.231 us; speedup vs baseline: 1.1459x; 1.0613x over previous
//
#include <hip/hip_runtime.h>
#include <math.h>

#define HH 256
#define WW 256
#define NF 352
#define NV 192
#define SIGMA_F 0.7f
// Keep a face for a subtile unless some edge has s <= CUT_S over the whole
// subtile => its prob < sigmoid(CUT_S) everywhere in the subtile (R12-proven).
#define CUT_S (-5.0f)

// Kernel 1: 512 blocks x 1024 threads (16 waves). Block -> (b, tile) with a
// BATCH-OFFSET SWIZZLE: b = blk>>8, t = (blk & 255) XOR-offset by 128 for b=1.
// Under round-robin dispatch CU = f(blk mod 256), so blk and blk+256 share a
// CU; without the swizzle both batches' copies of the SAME heavy central tile
// land on one CU (8 heavy waves/SIMD). With it, heavy pairs with peripheral
// -> straggler CU issue load halves. Pure heuristic: any dispatch mapping
// still computes identical outputs.
// Phase 1a: 192 vertex transforms -> LDS. Phase 1b: 352 face coeffs.
// Phase 2: per-8x8-subtile cull + ordered ballot compaction (waves 0-3).
// Phase 3: subtile q = wv&3, face quarter grp = wv>>2; fixed-order combine.
// Numerics byte-identical to R12.
__global__ __launch_bounds__(1024, 8) void sil_tile_kernel(
    const float* __restrict__ Rm, const float* __restrict__ obj_t,
    const float* __restrict__ obj_s, const float* __restrict__ verts,
    const int* __restrict__ faces, const float* __restrict__ Km,
    const float* __restrict__ keep_mask, const float* __restrict__ image_ref,
    const float* __restrict__ edt_src,
    float* __restrict__ out_image, float* __restrict__ loss_partials,
    float* __restrict__ out_iref, float* __restrict__ out_edt)
{
    __shared__ float2 vxy[NV];                // screen-space vertex positions
    __shared__ float4 coA[NF];                // (A0,B0,C0,A1) 16B stride
    __shared__ float4 coB[NF];                // (B1,C1,A2,B2)
    __shared__ float  coC[NF];                // (C2)
    __shared__ unsigned short flist[4][NF];   // per-subtile surviving faces
    __shared__ int fcount[4];
    __shared__ float accB[3][4 * 64];         // groups 1-3 partial products
    __shared__ float wsum[4];

    const int tid  = threadIdx.x;
    const int lane = tid & 63;
    const int wv   = tid >> 6;        // 0..15
    const int grp  = wv >> 2;         // face quarter 0..3
    const int q    = wv & 3;          // subtile 0..3
    const int blk  = blockIdx.x;      // 0..511
    const int b    = blk >> 8;
    const int t    = b ? ((blk + 128) & 255) : (blk & 255);  // batch-offset swizzle
    const int x0   = (t & 15) * 16, y0 = (t >> 4) * 16;
    const int sx   = (q & 1) * 8,  sy = (q >> 1) * 8;

    // ---- phase 1a: per-VERTEX transform (192 of them; R4 expression) ----
    if (tid < NV) {
        const float* Rb = Rm + b * 9;
        const float s  = obj_s[b];
        const float t0 = obj_t[b*3+0], t1 = obj_t[b*3+1], t2 = obj_t[b*3+2];
        const float K00 = Km[b*9+0], K02 = Km[b*9+2], K11 = Km[b*9+4], K12 = Km[b*9+5];
        const float* vp = verts + (b * NV + tid) * 3;
        float v0 = vp[0], v1 = vp[1], v2 = vp[2];
        float w0 = s * (v0*Rb[0] + v1*Rb[3] + v2*Rb[6] + t0);
        float w1 = s * (v0*Rb[1] + v1*Rb[4] + v2*Rb[7] + t1);
        float w2 = s * (v0*Rb[2] + v1*Rb[5] + v2*Rb[8] + t2);
        float X = (K00 * w0 / w2 + K02) * (float)WW;
        float Y = (K11 * w1 / w2 + K12) * (float)HH;
        vxy[tid] = {X, Y};
    }
    __syncthreads();

    // ---- phase 1b: per-face edge coefficients from LDS verts ----
    if (tid < NF) {
        const int f = tid;
        int i0 = faces[f*3+0], i1 = faces[f*3+1], i2 = faces[f*3+2];
        float2 P0 = vxy[i0], P1 = vxy[i1], P2 = vxy[i2];
        float X[3] = {P0.x, P1.x, P2.x};
        float Y[3] = {P0.y, P1.y, P2.y};
        float e01x = X[1]-X[0], e01y = Y[1]-Y[0];
        float e02x = X[2]-X[0], e02y = Y[2]-Y[0];
        float area2 = e01x*e02y - e01y*e02x;
        float orient = (area2 >= 0.0f) ? 1.0f : -1.0f;
        float E[9];
        #pragma unroll
        for (int k = 0; k < 3; ++k) {
            int k1 = (k == 2) ? 0 : k + 1;
            float ax = X[k], ay = Y[k];
            float ex = X[k1]-ax, ey = Y[k1]-ay;
            float inv = orient / (sqrtf(ex*ex + ey*ey) + 1e-8f) / SIGMA_F;
            E[k*3 + 0] = ex * inv;               // A (coeff of py)
            E[k*3 + 1] = -ey * inv;              // B (coeff of px)
            E[k*3 + 2] = inv * (ey*ax - ex*ay);  // C
        }
        coA[f] = {E[0], E[1], E[2], E[3]};
        coB[f] = {E[4], E[5], E[6], E[7]};
        coC[f] = E[8];
    }
    __syncthreads();

    // ---- phase 2: per-subtile (8x8) cull + ordered compaction (waves 0-3) ----
    if (grp == 0) {
        const float pxc = (float)(x0 + sx) + 4.0f;   // subtile center (half-ext 3.5<=4)
        const float pyc = (float)(y0 + sy) + 4.0f;
        int base = 0;
        #pragma unroll
        for (int r = 0; r < 6; ++r) {                // 6*64 = 384 >= NF
            int f = r * 64 + lane;
            bool keepf = false;
            if (f < NF) {
                float4 a4 = coA[f]; float4 b4 = coB[f]; float c2 = coC[f];
                // exact max of affine s over subtile rect (center +- 4)
                float m0 = fmaf(a4.x,pyc,fmaf(a4.y,pxc,a4.z)) + 4.0f*(fabsf(a4.x)+fabsf(a4.y));
                float m1 = fmaf(a4.w,pyc,fmaf(b4.x,pxc,b4.y)) + 4.0f*(fabsf(a4.w)+fabsf(b4.x));
                float m2 = fmaf(b4.z,pyc,fmaf(b4.w,pxc,c2 )) + 4.0f*(fabsf(b4.z)+fabsf(b4.w));
                keepf = fminf(m0, fminf(m1, m2)) > CUT_S;
            }
            unsigned long long m = __ballot(keepf);
            if (keepf) {
                int pre = __popcll(m & ((1ull << lane) - 1ull));
                flist[q][base + pre] = (unsigned short)f;
            }
            base += __popcll(m);
        }
        if (lane == 0) fcount[q] = base;
    }
    __syncthreads();

    // ---- phase 3: 1 px/lane, face loop split across the 4 wave groups ----
    const int n  = fcount[q];
    const int lo = (n * grp) >> 2;
    const int hi = (n * (grp + 1)) >> 2;
    const int lx = lane & 7, ly = lane >> 3;
    const float px = (float)(x0 + sx + lx) + 0.5f;
    const float py = (float)(y0 + sy + ly) + 0.5f;
    float acc = 1.0f;
    for (int i = lo; i < hi; ++i) {
        int idx = flist[q][i];                        // broadcast: conflict-free
        float4 a4 = coA[idx]; float4 b4 = coB[idx]; float c2 = coC[idx];
        float s0 = fmaf(a4.x, py, fmaf(a4.y, px, a4.z));
        float s1 = fmaf(a4.w, py, fmaf(b4.x, px, b4.y));
        float s2 = fmaf(b4.z, py, fmaf(b4.w, px, c2));
        // sig(s0)sig(s1)sig(s2) = rcp((1+e^-s0)(1+e^-s1)(1+e^-s2)): 4 trans not 6
        float e0 = __expf(-s0), e1 = __expf(-s1), e2 = __expf(-s2);
        float pr = __builtin_amdgcn_rcpf((1.0f+e0) * (1.0f+e1) * (1.0f+e2));
        pr = fminf(pr, 0.9999f);        // clip(prob, 0, 1-1e-4); inf den -> 0 ok
        acc *= (1.0f - pr);
    }
    if (grp != 0) accB[grp - 1][q * 64 + lane] = acc;
    __syncthreads();

    float sq = 0.0f;
    if (grp == 0) {
        // combine quarters in fixed order (deterministic)
        acc *= accB[0][q * 64 + lane];
        acc *= accB[1][q * 64 + lane];
        acc *= accB[2][q * 64 + lane];
        float sil = 1.0f - acc;
        const int gidx = b*HH*WW + (y0 + sy + ly)*WW + (x0 + sx + lx);
        float img = keep_mask[gidx] * sil;
        out_image[gidx] = img;
        float d = img - image_ref[gidx];
        sq = d * d;
    }

    // ---- passthrough copies (blk-based bijection over [0,131072); coalesced) ----
    if (tid < 512) {
        int g = blk * 256 + (tid & 255);
        if (tid < 256)      out_iref[g] = image_ref[g];
        else                out_edt[g]  = edt_src[g];
    }

    // ---- masked L2 loss partial (fixed-tree, grp0 waves only) ----
    #pragma unroll
    for (int o = 32; o > 0; o >>= 1) sq += __shfl_down(sq, o);
    if (grp == 0 && lane == 0) wsum[q] = sq;
    __syncthreads();
    if (tid == 0) loss_partials[blk] = wsum[0] + wsum[1] + wsum[2] + wsum[3];
}

// Kernel 2: edges (separable 7x7 maxpool - image) + final loss reduce (block 0).
// Byte-identical to the R4..R12-proven post kernel (partials sum is
// order-agnostic, so the sil-side swizzle needs no change here).
__global__ __launch_bounds__(256) void post_kernel(
    const float* __restrict__ image, const float* __restrict__ partials,
    float* __restrict__ out_loss, float* __restrict__ out_edges)
{
    __shared__ float tile[22][23];     // 16+2*3 halo, +1 col pad
    __shared__ float rmax[22][16];     // row-max over 7-wide window
    __shared__ float lsum[4];

    const int tid = threadIdx.x;
    const int b   = blockIdx.x >> 8;
    const int t   = blockIdx.x & 255;
    const int x0  = (t & 15) * 16, y0 = (t >> 4) * 16;
    const float* im = image + b * (HH*WW);

    // load 22x22 halo tile (OOB -> -inf; window always contains center pixel)
    for (int i = tid; i < 22*22; i += 256) {
        int r = i / 22, cidx = i % 22;
        int yy = y0 + r - 3, xx = x0 + cidx - 3;
        float v = -INFINITY;
        if (yy >= 0 && yy < HH && xx >= 0 && xx < WW) v = im[yy * WW + xx];
        tile[r][cidx] = v;
    }
    __syncthreads();

    // row pass
    for (int i = tid; i < 22*16; i += 256) {
        int r = i >> 4, c = i & 15;
        float m = tile[r][c];
        #pragma unroll
        for (int d = 1; d < 7; ++d) m = fmaxf(m, tile[r][c + d]);
        rmax[r][c] = m;
    }
    __syncthreads();

    // col pass + write edges
    const int lx = tid & 15, ly = tid >> 4;
    float m = rmax[ly][lx];
    #pragma unroll
    for (int d = 1; d < 7; ++d) m = fmaxf(m, rmax[ly + d][lx]);
    const int gidx = b * (HH*WW) + (y0 + ly) * WW + (x0 + lx);
    out_edges[gidx] = m - tile[ly + 3][lx + 3];

    // final loss reduction (block 0 only)
    if (blockIdx.x == 0) {
        float v = partials[tid] + partials[tid + 256];
        #pragma unroll
        for (int o = 32; o > 0; o >>= 1) v += __shfl_down(v, o);
        if ((tid & 63) == 0) lsum[tid >> 6] = v;
        __syncthreads();
        if (tid == 0)
            out_loss[0] = (lsum[0] + lsum[1] + lsum[2] + lsum[3]) * 0.5f; // mean over B=2
    }
}

extern "C" void kernel_launch(void* const* d_in, const int* in_sizes, int n_in,
                              void* d_out, int out_size, void* d_ws, size_t ws_size,
                              hipStream_t stream) {
    const float* Rm    = (const float*)d_in[0];
    const float* obj_t = (const float*)d_in[1];
    const float* obj_s = (const float*)d_in[2];
    const float* verts = (const float*)d_in[3];
    const int*   faces = (const int*)d_in[4];
    const float* Km    = (const float*)d_in[5];
    const float* keep  = (const float*)d_in[6];
    const float* iref  = (const float*)d_in[7];
    const float* edt   = (const float*)d_in[8];

    float* out       = (float*)d_out;
    float* out_loss  = out;
    float* out_image = out + 1;
    float* out_edges = out + 1 + 131072;
    float* out_iref  = out + 1 + 262144;
    float* out_edt   = out + 1 + 393216;
    float* partials  = (float*)d_ws;      // 512 floats

    sil_tile_kernel<<<512, 1024, 0, stream>>>(Rm, obj_t, obj_s, verts, faces, Km,
                                              keep, iref, edt,
                                              out_image, partials, out_iref, out_edt);
    post_kernel<<<512, 256, 0, stream>>>(out_image, partials, out_loss, out_edges);
}